// Round 12
// baseline (742.485 us; speedup 1.0000x reference)
//
#include <hip/hip_runtime.h>
#include <hip/hip_bf16.h>

#define NPTS 65536
#define NSAMP 16
#define CH 256
#define CNT (NPTS * NSAMP)   // 1048576
#define EPSV 1e-5f

typedef __hip_bfloat16 bf16;
typedef __attribute__((ext_vector_type(8))) short short8;
typedef __attribute__((ext_vector_type(4))) short sh4;
typedef __attribute__((ext_vector_type(4))) float floatx4;

__device__ __forceinline__ float b2f(bf16 v) { return __bfloat162float(v); }

// bf16 bits (as short) -> float
__device__ __forceinline__ float s2f(short v) {
    return __uint_as_float(((unsigned)(unsigned short)v) << 16);
}

__device__ __forceinline__ short f2bf_bits(float f) {
    bf16 h = __float2bfloat16(f);
    short s;
    __builtin_memcpy(&s, &h, 2);
    return s;
}

// ---------------------------------------------------------------------------
// fused0: block-role kernel.
//   bid <  1024       : statsp role (gather p[idx], BN_p stats, cache v into v4)
//   1024 <= bid <1120 : Wcat role (wq|wk|wv f32 -> bf16)
//   bid == 1120       : ww2b role
//   bid >  1120       : xb role (x f32 -> bf16, 8192 blocks)
// ---------------------------------------------------------------------------
__global__ __launch_bounds__(256) void fused0_kernel(
    const float* __restrict__ wq, const float* __restrict__ wk,
    const float* __restrict__ wv, const float* __restrict__ ww2,
    const float* __restrict__ x, const float* __restrict__ p,
    const int* __restrict__ idx,
    const float* __restrict__ wp1, const float* __restrict__ bp1,
    bf16* __restrict__ Wcat, bf16* __restrict__ ww2b, bf16* __restrict__ xb,
    float* __restrict__ statsP, float4* __restrict__ v4)
{
    __shared__ float red[4][6];
    int bid = blockIdx.x;

    if (bid < 1024) {
        // ---- statsp role ----
        float W00 = wp1[0], W01 = wp1[1], W02 = wp1[2];
        float W10 = wp1[3], W11 = wp1[4], W12 = wp1[5];
        float W20 = wp1[6], W21 = wp1[7], W22 = wp1[8];
        float B0 = bp1[0], B1 = bp1[1], B2 = bp1[2];

        float s0 = 0, s1 = 0, s2 = 0, q0 = 0, q1 = 0, q2 = 0;
        for (int r = bid * 256 + threadIdx.x; r < CNT; r += 1024 * 256) {
            int n = r >> 4;
            int i = idx[r];
            float a0 = p[3 * (size_t)i]     - p[3 * (size_t)n];
            float a1 = p[3 * (size_t)i + 1] - p[3 * (size_t)n + 1];
            float a2 = p[3 * (size_t)i + 2] - p[3 * (size_t)n + 2];
            float v0 = W00 * a0 + W01 * a1 + W02 * a2 + B0;
            float v1 = W10 * a0 + W11 * a1 + W12 * a2 + B1;
            float v2 = W20 * a0 + W21 * a1 + W22 * a2 + B2;
            s0 += v0; q0 += v0 * v0;
            s1 += v1; q1 += v1 * v1;
            s2 += v2; q2 += v2 * v2;
            v4[r] = make_float4(v0, v1, v2, 0.f);
        }
        float v[6] = {s0, s1, s2, q0, q1, q2};
        int wave = threadIdx.x >> 6;
#pragma unroll
        for (int k = 0; k < 6; k++) {
            float xv = v[k];
#pragma unroll
            for (int off = 32; off > 0; off >>= 1) xv += __shfl_down(xv, off);
            if ((threadIdx.x & 63) == 0) red[wave][k] = xv;
        }
        __syncthreads();
        if (threadIdx.x < 6) {
            float s = red[0][threadIdx.x] + red[1][threadIdx.x]
                    + red[2][threadIdx.x] + red[3][threadIdx.x];
            atomicAdd(&statsP[threadIdx.x * 16], s);   // separate cache lines
        }
    } else if (bid < 1120) {
        int e = ((bid - 1024) * 256 + threadIdx.x) * 8;   // e < 196608
        const float* src = (e < 65536) ? wq : (e < 131072) ? wk : wv;
        int off = e & 65535;
        float4 f0 = *(const float4*)(src + off);
        float4 f1 = *(const float4*)(src + off + 4);
        short8 r;
        r[0] = f2bf_bits(f0.x); r[1] = f2bf_bits(f0.y);
        r[2] = f2bf_bits(f0.z); r[3] = f2bf_bits(f0.w);
        r[4] = f2bf_bits(f1.x); r[5] = f2bf_bits(f1.y);
        r[6] = f2bf_bits(f1.z); r[7] = f2bf_bits(f1.w);
        *(short8*)(Wcat + e) = r;
    } else if (bid == 1120) {
        int e = threadIdx.x * 4;   // 256*4 = 1024 = 32*32
        float4 f = *(const float4*)(ww2 + e);
        sh4 r;
        r[0] = f2bf_bits(f.x); r[1] = f2bf_bits(f.y);
        r[2] = f2bf_bits(f.z); r[3] = f2bf_bits(f.w);
        *(sh4*)(ww2b + e) = r;
    } else {
        // x -> bf16: 16,777,216 elements, 8 per thread, 8192 blocks
        size_t e = ((size_t)(bid - 1121) * 256 + threadIdx.x) * 8;
        float4 f0 = *(const float4*)(x + e);
        float4 f1 = *(const float4*)(x + e + 4);
        short8 r;
        r[0] = f2bf_bits(f0.x); r[1] = f2bf_bits(f0.y);
        r[2] = f2bf_bits(f0.z); r[3] = f2bf_bits(f0.w);
        r[4] = f2bf_bits(f1.x); r[5] = f2bf_bits(f1.y);
        r[6] = f2bf_bits(f1.z); r[7] = f2bf_bits(f1.w);
        *(short8*)(xb + e) = r;
    }
}

// ---------------------------------------------------------------------------
// gemm: C[65536 x 768] = xb(bf16) @ Wcat^T, written as xq|xk|xv bf16 slices.
// 128x128 tiles, BK=32, LDS stride 40 (pad), 4 waves each 64x64.
// ---------------------------------------------------------------------------
__global__ __launch_bounds__(256) void gemm_kernel(
    const bf16* __restrict__ xb, const bf16* __restrict__ Wcat,
    const float* __restrict__ bq, const float* __restrict__ bk,
    const float* __restrict__ bv,
    bf16* __restrict__ xq, bf16* __restrict__ xk, bf16* __restrict__ xv)
{
    __shared__ __align__(16) bf16 As[128 * 40];
    __shared__ __align__(16) bf16 Bs[128 * 40];

    int t = threadIdx.x, lane = t & 63, wave = t >> 6;
    int m0 = blockIdx.x * 128;
    int y = blockIdx.y, n0 = y * 128;
    int srow = t >> 1, sch = t & 1;       // staging: 2 threads per row, 16 elems each
    int m = lane & 15, q = lane >> 4;
    int wm = wave >> 1, wn = wave & 1;

    floatx4 acc[4][4];
#pragma unroll
    for (int a = 0; a < 4; a++)
#pragma unroll
        for (int b = 0; b < 4; b++) acc[a][b] = (floatx4){0.f, 0.f, 0.f, 0.f};

    for (int kk = 0; kk < 256; kk += 32) {
        // stage A (bf16 copy)
        const bf16* ap = xb + (size_t)(m0 + srow) * 256 + kk + sch * 16;
        *(short8*)&As[srow * 40 + sch * 16]     = *(const short8*)ap;
        *(short8*)&As[srow * 40 + sch * 16 + 8] = *(const short8*)(ap + 8);
        // stage B (bf16 copy)
        const bf16* bp = Wcat + (size_t)(n0 + srow) * 256 + kk + sch * 16;
        *(short8*)&Bs[srow * 40 + sch * 16]     = *(const short8*)bp;
        *(short8*)&Bs[srow * 40 + sch * 16 + 8] = *(const short8*)(bp + 8);
        __syncthreads();

        short8 av[4], bvv[4];
#pragma unroll
        for (int mt = 0; mt < 4; mt++)
            av[mt] = *(const short8*)&As[(wm * 64 + mt * 16 + m) * 40 + q * 8];
#pragma unroll
        for (int nt = 0; nt < 4; nt++)
            bvv[nt] = *(const short8*)&Bs[(wn * 64 + nt * 16 + m) * 40 + q * 8];
#pragma unroll
        for (int mt = 0; mt < 4; mt++)
#pragma unroll
            for (int nt = 0; nt < 4; nt++)
                acc[mt][nt] = __builtin_amdgcn_mfma_f32_16x16x32_bf16(av[mt], bvv[nt], acc[mt][nt], 0, 0, 0);
        __syncthreads();
    }

    int z = y >> 1;
    bf16* O        = (z == 0) ? xq : (z == 1) ? xk : xv;
    const float* B = (z == 0) ? bq : (z == 1) ? bk : bv;
    int cbase = (y & 1) * 128 + wn * 64;
#pragma unroll
    for (int nt = 0; nt < 4; nt++) {
        int oc = cbase + nt * 16 + m;
        float bias = B[oc];
#pragma unroll
        for (int mt = 0; mt < 4; mt++) {
            int grow = m0 + wm * 64 + mt * 16 + q * 4;
#pragma unroll
            for (int i = 0; i < 4; i++)
                O[(size_t)(grow + i) * 256 + oc] = __float2bfloat16(acc[mt][nt][i] + bias);
        }
    }
}

// ---------------------------------------------------------------------------
// finalize: mean/var -> scale/shift (stride between channel accumulators)
// ---------------------------------------------------------------------------
__global__ void finalize_kernel(const float* __restrict__ stats,
                                const float* __restrict__ gamma,
                                const float* __restrict__ beta,
                                float* __restrict__ ss, int nch, int sstr)
{
    int c = threadIdx.x;
    if (c < nch) {
        float inv = 1.0f / (float)CNT;
        float mean = stats[c * sstr] * inv;
        float var = stats[(nch + c) * sstr] * inv - mean * mean;
        float sc = gamma[c] * rsqrtf(var + EPSV);
        ss[c] = sc;
        ss[nch + c] = beta[c] - mean * sc;
    }
}

// ---------------------------------------------------------------------------
// stats1: BN1 stats over w = xk[idx] - xq + p_r2, with BN_p applied inline
// to the cached pre-BN v4. Launched with 36KB dynamic LDS to force
// 2 blocks/CU = 8 gather-waves/CU (the measured L2 equilibrium from
// stats2's rounds 4/8/10 vs 5/7/11); unroll 8 for gather ILP.
// ---------------------------------------------------------------------------
__global__ __launch_bounds__(256) void stats1_kernel(
    const int* __restrict__ idx, const float4* __restrict__ r4,
    const bf16* __restrict__ xk, const bf16* __restrict__ xq,
    const float* __restrict__ wp2, const float* __restrict__ bp2,
    const float* __restrict__ ssP, float* __restrict__ stats1)
{
    __shared__ int idxs[1024];
    __shared__ float redS[8 * 264];
    __shared__ float redQ[8 * 264];

    int t = threadIdx.x;
    int r0 = blockIdx.x * 1024;
    for (int e = t; e < 1024; e += 256) idxs[e] = idx[r0 + e];

    int sub = t & 31, rl = t >> 5, cb = sub * 8;
    float w0[8], w1[8], w2[8], bc[8];
#pragma unroll
    for (int k = 0; k < 8; k++) {
        w0[k] = wp2[3 * (cb + k)];
        w1[k] = wp2[3 * (cb + k) + 1];
        w2[k] = wp2[3 * (cb + k) + 2];
        bc[k] = bp2[cb + k];
    }
    float scP0 = ssP[0], scP1 = ssP[1], scP2 = ssP[2];
    float shP0 = ssP[3], shP1 = ssP[4], shP2 = ssP[5];
    float s8[8] = {0, 0, 0, 0, 0, 0, 0, 0};
    float q8[8] = {0, 0, 0, 0, 0, 0, 0, 0};
    __syncthreads();

#pragma unroll 8
    for (int rr = rl; rr < 1024; rr += 8) {
        int r = r0 + rr;
        int i = idxs[rr];
        float4 va = r4[r];
        float rx = fmaxf(scP0 * va.x + shP0, 0.f);
        float ry = fmaxf(scP1 * va.y + shP1, 0.f);
        float rz = fmaxf(scP2 * va.z + shP2, 0.f);
        short8 kv = *(const short8*)(xk + (size_t)i * 256 + cb);
        short8 qv = *(const short8*)(xq + (size_t)(r >> 4) * 256 + cb);
#pragma unroll
        for (int k = 0; k < 8; k++) {
            float w = s2f(kv[k]) - s2f(qv[k]) + rx * w0[k] + ry * w1[k] + rz * w2[k] + bc[k];
            s8[k] += w; q8[k] += w * w;
        }
    }
#pragma unroll
    for (int k = 0; k < 8; k++) {
        redS[rl * 264 + cb + k] = s8[k];
        redQ[rl * 264 + cb + k] = q8[k];
    }
    __syncthreads();
    int c = t;
    float ts = 0, tq = 0;
#pragma unroll
    for (int sr = 0; sr < 8; sr++) {
        ts += redS[sr * 264 + c];
        tq += redQ[sr * 264 + c];
    }
    atomicAdd(&stats1[c], ts);
    atomicAdd(&stats1[256 + c], tq);
}

// ---------------------------------------------------------------------------
// stats2 (round-7/11 equilibrium: 256 threads, 2 blocks/CU, 8 waves/CU).
// Single-barrier double-buffer; ww1 fragments in VGPRs; BN_p inline on v4;
// nontemporal y2 stores.
// ---------------------------------------------------------------------------
__global__ __launch_bounds__(256) void stats2_kernel(
    const int* __restrict__ idx, const float4* __restrict__ r4,
    const bf16* __restrict__ xk, const bf16* __restrict__ xq,
    const float* __restrict__ wp2, const float* __restrict__ bp2,
    const float* __restrict__ ssP, const float* __restrict__ ss1,
    const float* __restrict__ ww1, const float* __restrict__ bw1,
    bf16* __restrict__ y2, float* __restrict__ stats2)
{
    __shared__ __align__(16) bf16 hb0[64 * 256];   // XOR-swizzled rows
    __shared__ __align__(16) bf16 hb1[64 * 256];

    int t = threadIdx.x;
    int lane = t & 63, wave = t >> 6;
    int m = lane & 15, q = lane >> 4;
    int sub = t & 31, rl = t >> 5, cb = sub * 8;
    int r0 = blockIdx.x * 1024;

    // ww1 B-fragments -> registers (f32 global, L2-resident, once per block)
    short8 bf0[8], bf1[8];
#pragma unroll
    for (int k = 0; k < 8; k++) {
        const float* w0p = ww1 + m * 256 + k * 32 + q * 8;
        const float* w1p = ww1 + (16 + m) * 256 + k * 32 + q * 8;
        float4 u0 = *(const float4*)(w0p);
        float4 u1 = *(const float4*)(w0p + 4);
        float4 u2 = *(const float4*)(w1p);
        float4 u3 = *(const float4*)(w1p + 4);
        short8 b0, b1;
        b0[0] = f2bf_bits(u0.x); b0[1] = f2bf_bits(u0.y);
        b0[2] = f2bf_bits(u0.z); b0[3] = f2bf_bits(u0.w);
        b0[4] = f2bf_bits(u1.x); b0[5] = f2bf_bits(u1.y);
        b0[6] = f2bf_bits(u1.z); b0[7] = f2bf_bits(u1.w);
        b1[0] = f2bf_bits(u2.x); b1[1] = f2bf_bits(u2.y);
        b1[2] = f2bf_bits(u2.z); b1[3] = f2bf_bits(u2.w);
        b1[4] = f2bf_bits(u3.x); b1[5] = f2bf_bits(u3.y);
        b1[6] = f2bf_bits(u3.z); b1[7] = f2bf_bits(u3.w);
        bf0[k] = b0; bf1[k] = b1;
    }

    float w0[8], w1[8], w2[8], bc[8], s1c[8], t1c[8];
#pragma unroll
    for (int k = 0; k < 8; k++) {
        w0[k] = wp2[3 * (cb + k)];
        w1[k] = wp2[3 * (cb + k) + 1];
        w2[k] = wp2[3 * (cb + k) + 2];
        bc[k] = bp2[cb + k];
        s1c[k] = ss1[cb + k];
        t1c[k] = ss1[256 + cb + k];
    }
    float scP0 = ssP[0], scP1 = ssP[1], scP2 = ssP[2];
    float shP0 = ssP[3], shP1 = ssP[4], shP2 = ssP[5];
    float bw0 = bw1[m], bw16 = bw1[16 + m];
    float jsum0 = 0, jsum1 = 0, jsq0 = 0, jsq1 = 0;
    int swh = cb ^ (rl << 3);        // staging write col (rr&7 == rl, const)
    int swa = (m & 7) << 3;          // MFMA read XOR ((wave*16+m)&7 == m&7)

    // prologue: stage tile 0 into hb0 (combined load+compute+write)
    {
#pragma unroll
        for (int u = 0; u < 8; u++) {
            int rr = rl + u * 8;
            int r = r0 + rr;
            int i = idx[r];
            float4 va = r4[r];
            float rx = fmaxf(scP0 * va.x + shP0, 0.f);
            float ry = fmaxf(scP1 * va.y + shP1, 0.f);
            float rz = fmaxf(scP2 * va.z + shP2, 0.f);
            short8 kv = *(const short8*)(xk + (size_t)i * 256 + cb);
            short8 qv = *(const short8*)(xq + (size_t)(r >> 4) * 256 + cb);
            short8 h;
#pragma unroll
            for (int k = 0; k < 8; k++) {
                float w = s2f(kv[k]) - s2f(qv[k]) + rx * w0[k] + ry * w1[k] + rz * w2[k] + bc[k];
                h[k] = f2bf_bits(fmaxf(s1c[k] * w + t1c[k], 0.f));
            }
            *(short8*)&hb0[rr * 256 + swh] = h;
        }
    }

    for (int it = 0; it < 16; ++it) {
        __syncthreads();   // staging of tile `it` complete (from prev iter / prologue)

        int rbn = r0 + (it + 1) * 64;
        bf16* hbw = (it & 1) ? hb0 : hb1;                 // next buffer
        const bf16* abase = ((it & 1) ? hb1 : hb0) + (wave * 16 + m) * 256;

        // A: issue next tile's random xk gathers (latency hides under B)
        short8 kvs[8];
        if (it < 15) {
#pragma unroll
            for (int u = 0; u < 8; u++) {
                int r = rbn + rl + u * 8;
                kvs[u] = *(const short8*)(xk + (size_t)idx[r] * 256 + cb);
            }
        }

        // B: MFMA from current buffer + nontemporal y2 stores
        floatx4 a0 = (floatx4){bw0, bw0, bw0, bw0};
        floatx4 a1 = (floatx4){bw16, bw16, bw16, bw16};
#pragma unroll
        for (int k = 0; k < 8; k++) {
            int col = (k * 32 + q * 8) ^ swa;
            short8 af = *(const short8*)(abase + col);
            a0 = __builtin_amdgcn_mfma_f32_16x16x32_bf16(af, bf0[k], a0, 0, 0, 0);
            a1 = __builtin_amdgcn_mfma_f32_16x16x32_bf16(af, bf1[k], a1, 0, 0, 0);
        }
        int grow = r0 + it * 64 + wave * 16 + q * 4;
#pragma unroll
        for (int ii = 0; ii < 4; ii++) {
            float y0 = a0[ii];
            float y1 = a1[ii];
            jsum0 += y0; jsq0 += y0 * y0;
            jsum1 += y1; jsq1 += y1 * y1;
            __builtin_nontemporal_store(f2bf_bits(y0),
                (short*)(y2 + (size_t)(grow + ii) * 32 + m));
            __builtin_nontemporal_store(f2bf_bits(y1),
                (short*)(y2 + (size_t)(grow + ii) * 32 + 16 + m));
        }

        // C: finish next tile's rows (cache-friendly loads) and write to LDS
        if (it < 15) {
#pragma unroll
            for (int u = 0; u < 8; u++) {
                int rr = rl + u * 8;
                int r = rbn + rr;
                float4 va = r4[r];
                float rx = fmaxf(scP0 * va.x + shP0, 0.f);
                float ry = fmaxf(scP1 * va.y + shP1, 0.f);
                float rz = fmaxf(scP2 * va.z + shP2, 0.f);
                short8 qv = *(const short8*)(xq + (size_t)(r >> 4) * 256 + cb);
                short8 h;
#pragma unroll
                for (int k = 0; k < 8; k++) {
                    float w = s2f(kvs[u][k]) - s2f(qv[k]) + rx * w0[k] + ry * w1[k] + rz * w2[k] + bc[k];
                    h[k] = f2bf_bits(fmaxf(s1c[k] * w + t1c[k], 0.f));
                }
                *(short8*)&hbw[rr * 256 + swh] = h;
            }
        }
    }

    jsum0 += __shfl_xor(jsum0, 16); jsum0 += __shfl_xor(jsum0, 32);
    jsum1 += __shfl_xor(jsum1, 16); jsum1 += __shfl_xor(jsum1, 32);
    jsq0  += __shfl_xor(jsq0, 16);  jsq0  += __shfl_xor(jsq0, 32);
    jsq1  += __shfl_xor(jsq1, 16);  jsq1  += __shfl_xor(jsq1, 32);
    if (q == 0) {
        atomicAdd(&stats2[m], jsum0);
        atomicAdd(&stats2[16 + m], jsum1);
        atomicAdd(&stats2[32 + m], jsq0);
        atomicAdd(&stats2[48 + m], jsq1);
    }
}

// ---------------------------------------------------------------------------
// final: wave-per-point, zero barriers; BN_p inline; y2 interleaved [CNT][32].
// Launched with 32KB dynamic LDS to cap at 3 blocks/CU = 12 gather-waves/CU
// (xv gather L2-thrash mitigation per the stats2 concurrency law).
// ---------------------------------------------------------------------------
__global__ __launch_bounds__(256) void final_kernel(
    const int* __restrict__ idx, const float4* __restrict__ r4,
    const bf16* __restrict__ xv,
    const float* __restrict__ wp2, const float* __restrict__ bp2,
    const bf16* __restrict__ y2, const float* __restrict__ ss2,
    const bf16* __restrict__ ww2b, const float* __restrict__ bw2,
    const float* __restrict__ ssP, float* __restrict__ out)
{
    __shared__ __align__(16) float wsm[4][16][36];  // [wave][s][j] stride 36 (144B, 16-aligned)
    __shared__ float Asm[4][4][32];                 // [wave][d][j]

    int t = threadIdx.x, wave = t >> 6, lane = t & 63;
    int m = lane & 15, q = lane >> 4;

    // logits B-fragments: ww2b rows m / 16+m (output cols), K-span q*8
    short8 bf0 = *(const short8*)(ww2b + m * 32 + q * 8);
    short8 bf1 = *(const short8*)(ww2b + (16 + m) * 32 + q * 8);
    float bwj0 = bw2[m], bwj1 = bw2[16 + m];

    float s2c[8], t2c[8];
#pragma unroll
    for (int k = 0; k < 8; k++) {
        s2c[k] = ss2[q * 8 + k];
        t2c[k] = ss2[32 + q * 8 + k];
    }
    float scP0 = ssP[0], scP1 = ssP[1], scP2 = ssP[2];
    float shP0 = ssP[3], shP1 = ssP[4], shP2 = ssP[5];

    int c0 = lane * 4;          // this lane's 4 output channels
    int j4 = (lane & 7) * 4;    // j = c & 31
    float wpc0[4], wpc1[4], wpc2[4], bpc[4];
#pragma unroll
    for (int k = 0; k < 4; k++) {
        wpc0[k] = wp2[(c0 + k) * 3];
        wpc1[k] = wp2[(c0 + k) * 3 + 1];
        wpc2[k] = wp2[(c0 + k) * 3 + 2];
        bpc[k]  = bp2[c0 + k];
    }

    int pbase = (blockIdx.x * 4 + wave) * 8;
    for (int pp = 0; pp < 8; pp++) {
        int n = pbase + pp;
        size_t rbase = (size_t)n * 16;

        int iv = idx[rbase + m];   // lanes 0..15 hold the 16 neighbor ids

        // A-frag: z[s=m][u=q*8+k] = relu(bn2(y2))
        short8 yv = *(const short8*)(y2 + (rbase + m) * 32 + q * 8);
        short8 av;
#pragma unroll
        for (int k = 0; k < 8; k++)
            av[k] = f2bf_bits(fmaxf(s2c[k] * s2f(yv[k]) + t2c[k], 0.f));

        floatx4 l0 = (floatx4){bwj0, bwj0, bwj0, bwj0};
        floatx4 l1 = (floatx4){bwj1, bwj1, bwj1, bwj1};
        l0 = __builtin_amdgcn_mfma_f32_16x16x32_bf16(av, bf0, l0, 0, 0, 0);
        l1 = __builtin_amdgcn_mfma_f32_16x16x32_bf16(av, bf1, l1, 0, 0, 0);
        // lane (m,q), reg i: l0[i] = lb[s=q*4+i][j=m], l1[i] = lb[s][j=16+m]

        // softmax over s per column j: lanes {m, m+16, m+32, m+48} hold a column
        float mx0 = fmaxf(fmaxf(l0[0], l0[1]), fmaxf(l0[2], l0[3]));
        float mx1 = fmaxf(fmaxf(l1[0], l1[1]), fmaxf(l1[2], l1[3]));
        mx0 = fmaxf(mx0, __shfl_xor(mx0, 16));
        mx0 = fmaxf(mx0, __shfl_xor(mx0, 32));
        mx1 = fmaxf(mx1, __shfl_xor(mx1, 16));
        mx1 = fmaxf(mx1, __shfl_xor(mx1, 32));
        float w0[4], w1[4];
        float sum0 = 0.f, sum1 = 0.f;
#pragma unroll
        for (int i = 0; i < 4; i++) {
            w0[i] = __expf(l0[i] - mx0); sum0 += w0[i];
            w1[i] = __expf(l1[i] - mx1); sum1 += w1[i];
        }
        sum0 += __shfl_xor(sum0, 16); sum0 += __shfl_xor(sum0, 32);
        sum1 += __shfl_xor(sum1, 16); sum1 += __shfl_xor(sum1, 32);
        float inv0 = 1.f / sum0, inv1 = 1.f / sum1;

        // normalize + A[d][j] partials + stash w to LDS
        float A00 = 0, A10 = 0, A20 = 0, A30 = 0;
        float A01 = 0, A11 = 0, A21 = 0, A31 = 0;
#pragma unroll
        for (int i = 0; i < 4; i++) {
            w0[i] *= inv0; w1[i] *= inv1;
            float4 va = r4[rbase + q * 4 + i];
            float rx = fmaxf(scP0 * va.x + shP0, 0.f);
            float ry = fmaxf(scP1 * va.y + shP1, 0.f);
            float rz = fmaxf(scP2 * va.z + shP2, 0.f);
            A00 += rx * w0[i]; A10 += ry * w0[i];
            A20 += rz * w0[i]; A30 += w0[i];
            A01 += rx * w1[i]; A11 += ry * w1[i];
            A21 += rz * w1[i]; A31 += w1[i];
            wsm[wave][q * 4 + i][m]      = w0[i];
            wsm[wave][q * 4 + i][16 + m] = w1[i];
        }
        A00 += __shfl_xor(A00, 16); A00 += __shfl_xor(A00, 32);
        A10 += __shfl_xor(A10, 16); A10 += __shfl_xor(A10, 32);
        A20 += __shfl_xor(A20, 16); A20 += __shfl_xor(A20, 32);
        A30 += __shfl_xor(A30, 16); A30 += __shfl_xor(A30, 32);
        A01 += __shfl_xor(A01, 16); A01 += __shfl_xor(A01, 32);
        A11 += __shfl_xor(A11, 16); A11 += __shfl_xor(A11, 32);
        A21 += __shfl_xor(A21, 16); A21 += __shfl_xor(A21, 32);
        A31 += __shfl_xor(A31, 16); A31 += __shfl_xor(A31, 32);
        if (q == 0) {
            Asm[wave][0][m] = A00; Asm[wave][1][m] = A10;
            Asm[wave][2][m] = A20; Asm[wave][3][m] = A30;
            Asm[wave][0][16 + m] = A01; Asm[wave][1][16 + m] = A11;
            Asm[wave][2][16 + m] = A21; Asm[wave][3][16 + m] = A31;
        }
        // wave-private LDS: in-order DS pipe + compiler lgkmcnt ordering,
        // no __syncthreads needed.

        // phase D: weighted neighbor sum over the gathered xv rows
        float acc0 = 0, acc1 = 0, acc2 = 0, acc3 = 0;
#pragma unroll
        for (int s = 0; s < 16; s++) {
            int i = __builtin_amdgcn_readlane(iv, s);   // uniform -> SGPR base
            sh4 vv = *(const sh4*)(xv + (size_t)i * 256 + c0);
            float4 wv = *(const float4*)&wsm[wave][s][j4];
            acc0 += s2f(vv[0]) * wv.x;
            acc1 += s2f(vv[1]) * wv.y;
            acc2 += s2f(vv[2]) * wv.z;
            acc3 += s2f(vv[3]) * wv.w;
        }

        float res[4] = {acc0, acc1, acc2, acc3};
#pragma unroll
        for (int k = 0; k < 4; k++) {
            int j = j4 + k;
            res[k] += wpc0[k] * Asm[wave][0][j] + wpc1[k] * Asm[wave][1][j]
                    + wpc2[k] * Asm[wave][2][j] + bpc[k]  * Asm[wave][3][j];
        }
        *(float4*)(out + (size_t)n * 256 + c0) =
            make_float4(res[0], res[1], res[2], res[3]);
    }
}

// ---------------------------------------------------------------------------
extern "C" void kernel_launch(void* const* d_in, const int* in_sizes, int n_in,
                              void* d_out, int out_size, void* d_ws, size_t ws_size,
                              hipStream_t stream) {
    (void)in_sizes; (void)n_in; (void)out_size; (void)ws_size;

    const float* p   = (const float*)d_in[0];
    const float* x   = (const float*)d_in[1];
    const int*   idx = (const int*)d_in[2];
    const float* wq  = (const float*)d_in[3];  const float* bq  = (const float*)d_in[4];
    const float* wk  = (const float*)d_in[5];  const float* bk  = (const float*)d_in[6];
    const float* wv  = (const float*)d_in[7];  const float* bv  = (const float*)d_in[8];
    const float* wp1 = (const float*)d_in[9];  const float* bp1 = (const float*)d_in[10];
    const float* gp  = (const float*)d_in[11]; const float* btp = (const float*)d_in[12];
    const float* wp2 = (const float*)d_in[13]; const float* bp2 = (const float*)d_in[14];
    const float* g1  = (const float*)d_in[15]; const float* b1  = (const float*)d_in[16];
    const float* ww1 = (const float*)d_in[17]; const float* bw1 = (const float*)d_in[18];
    const float* g2  = (const float*)d_in[19]; const float* b2  = (const float*)d_in[20];
    const float* ww2 = (const float*)d_in[21]; const float* bw2 = (const float*)d_in[22];
    float* out = (float*)d_out;

    // workspace layout
    float* fws    = (float*)d_ws;
    float* statsP = fws;            // 96 floats: 6 accumulators at stride 16
    float* ssP    = fws + 96;       // 6
    float* stats1 = fws + 112;      // 512
    float* ss1    = fws + 624;      // 512
    float* stats2 = fws + 1136;     // 64
    float* ss2    = fws + 1200;     // 64  (ends at float 1264 = byte 5056)
    bf16* ww2b = (bf16*)((char*)d_ws + 6144);          // 1024 bf16 = 2048 B (ends at 8192)
    bf16* Wcat = (bf16*)((char*)d_ws + 8192);          // 768*256 bf16 = 393216 B
    bf16* xq = (bf16*)((char*)d_ws + 401408);
    bf16* xk = xq + (size_t)NPTS * CH;
    bf16* xv = xk + (size_t)NPTS * CH;
    bf16* y2 = xv + (size_t)NPTS * CH;                 // CNT*32 bf16 (64 MB)
    float4* r4 = (float4*)(y2 + (size_t)CNT * 32);     // CNT float4
    // xb (bf16 x, 32 MB) aliases the y2 region: needed only between fused0
    // and gemm; y2 is first written much later (stats2).
    bf16* xb = y2;
    // total ~185 MB

    hipMemsetAsync(d_ws, 0, 8192, stream);

    fused0_kernel<<<1024 + 97 + 8192, 256, 0, stream>>>(
        wq, wk, wv, ww2, x, p, idx, wp1, bp1, Wcat, ww2b, xb, statsP, r4);
    gemm_kernel<<<dim3(512, 6), 256, 0, stream>>>(xb, Wcat, bq, bk, bv, xq, xk, xv);
    finalize_kernel<<<1, 256, 0, stream>>>(statsP, gp, btp, ssP, 3, 16);
    // stats1: +36KB dynamic LDS -> 57.8KB/block -> 2 blocks/CU (8 gather-waves)
    stats1_kernel<<<1024, 256, 36864, stream>>>(idx, r4, xk, xq, wp2, bp2, ssP, stats1);
    finalize_kernel<<<1, 256, 0, stream>>>(stats1, g1, b1, ss1, 256, 1);
    stats2_kernel<<<1024, 256, 0, stream>>>(idx, r4, xk, xq, wp2, bp2, ssP, ss1, ww1, bw1, y2, stats2);
    finalize_kernel<<<1, 256, 0, stream>>>(stats2, g2, b2, ss2, 32, 1);
    // final: +32KB dynamic LDS -> 44KB/block -> 3 blocks/CU (12 gather-waves)
    final_kernel<<<NPTS / 32, 256, 32768, stream>>>(idx, r4, xv, wp2, bp2, y2, ss2, ww2b, bw2, ssP, out);
}

// Round 13
// 641.950 us; speedup vs baseline: 1.1566x; 1.1566x over previous
//
#include <hip/hip_runtime.h>
#include <hip/hip_bf16.h>

#define NPTS 65536
#define NSAMP 16
#define CH 256
#define CNT (NPTS * NSAMP)   // 1048576
#define EPSV 1e-5f

typedef __hip_bfloat16 bf16;
typedef __attribute__((ext_vector_type(8))) short short8;
typedef __attribute__((ext_vector_type(4))) short sh4;
typedef __attribute__((ext_vector_type(4))) float floatx4;

__device__ __forceinline__ float b2f(bf16 v) { return __bfloat162float(v); }

// bf16 bits (as short) -> float
__device__ __forceinline__ float s2f(short v) {
    return __uint_as_float(((unsigned)(unsigned short)v) << 16);
}

__device__ __forceinline__ short f2bf_bits(float f) {
    bf16 h = __float2bfloat16(f);
    short s;
    __builtin_memcpy(&s, &h, 2);
    return s;
}

// ---------------------------------------------------------------------------
// fused0: block-role kernel.
//   bid <  1024       : statsp role (gather p[idx], BN_p stats, cache v into v4)
//   1024 <= bid <1120 : Wcat role (wq|wk|wv f32 -> bf16)
//   bid == 1120       : ww2b role
//   bid >  1120       : xb role (x f32 -> bf16, 8192 blocks)
// ---------------------------------------------------------------------------
__global__ __launch_bounds__(256) void fused0_kernel(
    const float* __restrict__ wq, const float* __restrict__ wk,
    const float* __restrict__ wv, const float* __restrict__ ww2,
    const float* __restrict__ x, const float* __restrict__ p,
    const int* __restrict__ idx,
    const float* __restrict__ wp1, const float* __restrict__ bp1,
    bf16* __restrict__ Wcat, bf16* __restrict__ ww2b, bf16* __restrict__ xb,
    float* __restrict__ statsP, float4* __restrict__ v4)
{
    __shared__ float red[4][6];
    int bid = blockIdx.x;

    if (bid < 1024) {
        // ---- statsp role ----
        float W00 = wp1[0], W01 = wp1[1], W02 = wp1[2];
        float W10 = wp1[3], W11 = wp1[4], W12 = wp1[5];
        float W20 = wp1[6], W21 = wp1[7], W22 = wp1[8];
        float B0 = bp1[0], B1 = bp1[1], B2 = bp1[2];

        float s0 = 0, s1 = 0, s2 = 0, q0 = 0, q1 = 0, q2 = 0;
        for (int r = bid * 256 + threadIdx.x; r < CNT; r += 1024 * 256) {
            int n = r >> 4;
            int i = idx[r];
            float a0 = p[3 * (size_t)i]     - p[3 * (size_t)n];
            float a1 = p[3 * (size_t)i + 1] - p[3 * (size_t)n + 1];
            float a2 = p[3 * (size_t)i + 2] - p[3 * (size_t)n + 2];
            float v0 = W00 * a0 + W01 * a1 + W02 * a2 + B0;
            float v1 = W10 * a0 + W11 * a1 + W12 * a2 + B1;
            float v2 = W20 * a0 + W21 * a1 + W22 * a2 + B2;
            s0 += v0; q0 += v0 * v0;
            s1 += v1; q1 += v1 * v1;
            s2 += v2; q2 += v2 * v2;
            v4[r] = make_float4(v0, v1, v2, 0.f);
        }
        float v[6] = {s0, s1, s2, q0, q1, q2};
        int wave = threadIdx.x >> 6;
#pragma unroll
        for (int k = 0; k < 6; k++) {
            float xv = v[k];
#pragma unroll
            for (int off = 32; off > 0; off >>= 1) xv += __shfl_down(xv, off);
            if ((threadIdx.x & 63) == 0) red[wave][k] = xv;
        }
        __syncthreads();
        if (threadIdx.x < 6) {
            float s = red[0][threadIdx.x] + red[1][threadIdx.x]
                    + red[2][threadIdx.x] + red[3][threadIdx.x];
            atomicAdd(&statsP[threadIdx.x * 16], s);   // separate cache lines
        }
    } else if (bid < 1120) {
        int e = ((bid - 1024) * 256 + threadIdx.x) * 8;   // e < 196608
        const float* src = (e < 65536) ? wq : (e < 131072) ? wk : wv;
        int off = e & 65535;
        float4 f0 = *(const float4*)(src + off);
        float4 f1 = *(const float4*)(src + off + 4);
        short8 r;
        r[0] = f2bf_bits(f0.x); r[1] = f2bf_bits(f0.y);
        r[2] = f2bf_bits(f0.z); r[3] = f2bf_bits(f0.w);
        r[4] = f2bf_bits(f1.x); r[5] = f2bf_bits(f1.y);
        r[6] = f2bf_bits(f1.z); r[7] = f2bf_bits(f1.w);
        *(short8*)(Wcat + e) = r;
    } else if (bid == 1120) {
        int e = threadIdx.x * 4;   // 256*4 = 1024 = 32*32
        float4 f = *(const float4*)(ww2 + e);
        sh4 r;
        r[0] = f2bf_bits(f.x); r[1] = f2bf_bits(f.y);
        r[2] = f2bf_bits(f.z); r[3] = f2bf_bits(f.w);
        *(sh4*)(ww2b + e) = r;
    } else {
        // x -> bf16: 16,777,216 elements, 8 per thread, 8192 blocks
        size_t e = ((size_t)(bid - 1121) * 256 + threadIdx.x) * 8;
        float4 f0 = *(const float4*)(x + e);
        float4 f1 = *(const float4*)(x + e + 4);
        short8 r;
        r[0] = f2bf_bits(f0.x); r[1] = f2bf_bits(f0.y);
        r[2] = f2bf_bits(f0.z); r[3] = f2bf_bits(f0.w);
        r[4] = f2bf_bits(f1.x); r[5] = f2bf_bits(f1.y);
        r[6] = f2bf_bits(f1.z); r[7] = f2bf_bits(f1.w);
        *(short8*)(xb + e) = r;
    }
}

// ---------------------------------------------------------------------------
// gemm: C[65536 x 768] = xb(bf16) @ Wcat^T, written as xq|xk|xv bf16 slices.
// 128x128 tiles, BK=32, LDS stride 40 (pad), 4 waves each 64x64.
// ---------------------------------------------------------------------------
__global__ __launch_bounds__(256) void gemm_kernel(
    const bf16* __restrict__ xb, const bf16* __restrict__ Wcat,
    const float* __restrict__ bq, const float* __restrict__ bk,
    const float* __restrict__ bv,
    bf16* __restrict__ xq, bf16* __restrict__ xk, bf16* __restrict__ xv)
{
    __shared__ __align__(16) bf16 As[128 * 40];
    __shared__ __align__(16) bf16 Bs[128 * 40];

    int t = threadIdx.x, lane = t & 63, wave = t >> 6;
    int m0 = blockIdx.x * 128;
    int y = blockIdx.y, n0 = y * 128;
    int srow = t >> 1, sch = t & 1;       // staging: 2 threads per row, 16 elems each
    int m = lane & 15, q = lane >> 4;
    int wm = wave >> 1, wn = wave & 1;

    floatx4 acc[4][4];
#pragma unroll
    for (int a = 0; a < 4; a++)
#pragma unroll
        for (int b = 0; b < 4; b++) acc[a][b] = (floatx4){0.f, 0.f, 0.f, 0.f};

    for (int kk = 0; kk < 256; kk += 32) {
        // stage A (bf16 copy)
        const bf16* ap = xb + (size_t)(m0 + srow) * 256 + kk + sch * 16;
        *(short8*)&As[srow * 40 + sch * 16]     = *(const short8*)ap;
        *(short8*)&As[srow * 40 + sch * 16 + 8] = *(const short8*)(ap + 8);
        // stage B (bf16 copy)
        const bf16* bp = Wcat + (size_t)(n0 + srow) * 256 + kk + sch * 16;
        *(short8*)&Bs[srow * 40 + sch * 16]     = *(const short8*)bp;
        *(short8*)&Bs[srow * 40 + sch * 16 + 8] = *(const short8*)(bp + 8);
        __syncthreads();

        short8 av[4], bvv[4];
#pragma unroll
        for (int mt = 0; mt < 4; mt++)
            av[mt] = *(const short8*)&As[(wm * 64 + mt * 16 + m) * 40 + q * 8];
#pragma unroll
        for (int nt = 0; nt < 4; nt++)
            bvv[nt] = *(const short8*)&Bs[(wn * 64 + nt * 16 + m) * 40 + q * 8];
#pragma unroll
        for (int mt = 0; mt < 4; mt++)
#pragma unroll
            for (int nt = 0; nt < 4; nt++)
                acc[mt][nt] = __builtin_amdgcn_mfma_f32_16x16x32_bf16(av[mt], bvv[nt], acc[mt][nt], 0, 0, 0);
        __syncthreads();
    }

    int z = y >> 1;
    bf16* O        = (z == 0) ? xq : (z == 1) ? xk : xv;
    const float* B = (z == 0) ? bq : (z == 1) ? bk : bv;
    int cbase = (y & 1) * 128 + wn * 64;
#pragma unroll
    for (int nt = 0; nt < 4; nt++) {
        int oc = cbase + nt * 16 + m;
        float bias = B[oc];
#pragma unroll
        for (int mt = 0; mt < 4; mt++) {
            int grow = m0 + wm * 64 + mt * 16 + q * 4;
#pragma unroll
            for (int i = 0; i < 4; i++)
                O[(size_t)(grow + i) * 256 + oc] = __float2bfloat16(acc[mt][nt][i] + bias);
        }
    }
}

// ---------------------------------------------------------------------------
// finalize: mean/var -> scale/shift (stride between channel accumulators)
// ---------------------------------------------------------------------------
__global__ void finalize_kernel(const float* __restrict__ stats,
                                const float* __restrict__ gamma,
                                const float* __restrict__ beta,
                                float* __restrict__ ss, int nch, int sstr)
{
    int c = threadIdx.x;
    if (c < nch) {
        float inv = 1.0f / (float)CNT;
        float mean = stats[c * sstr] * inv;
        float var = stats[(nch + c) * sstr] * inv - mean * mean;
        float sc = gamma[c] * rsqrtf(var + EPSV);
        ss[c] = sc;
        ss[nch + c] = beta[c] - mean * sc;
    }
}

// ---------------------------------------------------------------------------
// stats1: BN1 stats over w = xk[idx] - xq + p_r2, with BN_p applied inline
// to the cached pre-BN v4. Full occupancy (round-12 showed the 2-blocks/CU
// cap HURTS this kernel: pure gather+VALU, no compute phase to hide latency
// under -> needs TLP; its FETCH is already at the ~260MB equilibrium).
// ---------------------------------------------------------------------------
__global__ __launch_bounds__(256) void stats1_kernel(
    const int* __restrict__ idx, const float4* __restrict__ r4,
    const bf16* __restrict__ xk, const bf16* __restrict__ xq,
    const float* __restrict__ wp2, const float* __restrict__ bp2,
    const float* __restrict__ ssP, float* __restrict__ stats1)
{
    __shared__ int idxs[1024];
    __shared__ float redS[8 * 264];
    __shared__ float redQ[8 * 264];

    int t = threadIdx.x;
    int r0 = blockIdx.x * 1024;
    for (int e = t; e < 1024; e += 256) idxs[e] = idx[r0 + e];

    int sub = t & 31, rl = t >> 5, cb = sub * 8;
    float w0[8], w1[8], w2[8], bc[8];
#pragma unroll
    for (int k = 0; k < 8; k++) {
        w0[k] = wp2[3 * (cb + k)];
        w1[k] = wp2[3 * (cb + k) + 1];
        w2[k] = wp2[3 * (cb + k) + 2];
        bc[k] = bp2[cb + k];
    }
    float scP0 = ssP[0], scP1 = ssP[1], scP2 = ssP[2];
    float shP0 = ssP[3], shP1 = ssP[4], shP2 = ssP[5];
    float s8[8] = {0, 0, 0, 0, 0, 0, 0, 0};
    float q8[8] = {0, 0, 0, 0, 0, 0, 0, 0};
    __syncthreads();

#pragma unroll 4
    for (int rr = rl; rr < 1024; rr += 8) {
        int r = r0 + rr;
        int i = idxs[rr];
        float4 va = r4[r];
        float rx = fmaxf(scP0 * va.x + shP0, 0.f);
        float ry = fmaxf(scP1 * va.y + shP1, 0.f);
        float rz = fmaxf(scP2 * va.z + shP2, 0.f);
        short8 kv = *(const short8*)(xk + (size_t)i * 256 + cb);
        short8 qv = *(const short8*)(xq + (size_t)(r >> 4) * 256 + cb);
#pragma unroll
        for (int k = 0; k < 8; k++) {
            float w = s2f(kv[k]) - s2f(qv[k]) + rx * w0[k] + ry * w1[k] + rz * w2[k] + bc[k];
            s8[k] += w; q8[k] += w * w;
        }
    }
#pragma unroll
    for (int k = 0; k < 8; k++) {
        redS[rl * 264 + cb + k] = s8[k];
        redQ[rl * 264 + cb + k] = q8[k];
    }
    __syncthreads();
    int c = t;
    float ts = 0, tq = 0;
#pragma unroll
    for (int sr = 0; sr < 8; sr++) {
        ts += redS[sr * 264 + c];
        tq += redQ[sr * 264 + c];
    }
    atomicAdd(&stats1[c], ts);
    atomicAdd(&stats1[256 + c], tq);
}

// ---------------------------------------------------------------------------
// stats2 (round-7/11 equilibrium: 256 threads, 2 blocks/CU, 8 waves/CU).
// Single-barrier double-buffer; ww1 fragments in VGPRs; BN_p inline on v4;
// nontemporal y2 stores.
// ---------------------------------------------------------------------------
__global__ __launch_bounds__(256) void stats2_kernel(
    const int* __restrict__ idx, const float4* __restrict__ r4,
    const bf16* __restrict__ xk, const bf16* __restrict__ xq,
    const float* __restrict__ wp2, const float* __restrict__ bp2,
    const float* __restrict__ ssP, const float* __restrict__ ss1,
    const float* __restrict__ ww1, const float* __restrict__ bw1,
    bf16* __restrict__ y2, float* __restrict__ stats2)
{
    __shared__ __align__(16) bf16 hb0[64 * 256];   // XOR-swizzled rows
    __shared__ __align__(16) bf16 hb1[64 * 256];

    int t = threadIdx.x;
    int lane = t & 63, wave = t >> 6;
    int m = lane & 15, q = lane >> 4;
    int sub = t & 31, rl = t >> 5, cb = sub * 8;
    int r0 = blockIdx.x * 1024;

    // ww1 B-fragments -> registers (f32 global, L2-resident, once per block)
    short8 bf0[8], bf1[8];
#pragma unroll
    for (int k = 0; k < 8; k++) {
        const float* w0p = ww1 + m * 256 + k * 32 + q * 8;
        const float* w1p = ww1 + (16 + m) * 256 + k * 32 + q * 8;
        float4 u0 = *(const float4*)(w0p);
        float4 u1 = *(const float4*)(w0p + 4);
        float4 u2 = *(const float4*)(w1p);
        float4 u3 = *(const float4*)(w1p + 4);
        short8 b0, b1;
        b0[0] = f2bf_bits(u0.x); b0[1] = f2bf_bits(u0.y);
        b0[2] = f2bf_bits(u0.z); b0[3] = f2bf_bits(u0.w);
        b0[4] = f2bf_bits(u1.x); b0[5] = f2bf_bits(u1.y);
        b0[6] = f2bf_bits(u1.z); b0[7] = f2bf_bits(u1.w);
        b1[0] = f2bf_bits(u2.x); b1[1] = f2bf_bits(u2.y);
        b1[2] = f2bf_bits(u2.z); b1[3] = f2bf_bits(u2.w);
        b1[4] = f2bf_bits(u3.x); b1[5] = f2bf_bits(u3.y);
        b1[6] = f2bf_bits(u3.z); b1[7] = f2bf_bits(u3.w);
        bf0[k] = b0; bf1[k] = b1;
    }

    float w0[8], w1[8], w2[8], bc[8], s1c[8], t1c[8];
#pragma unroll
    for (int k = 0; k < 8; k++) {
        w0[k] = wp2[3 * (cb + k)];
        w1[k] = wp2[3 * (cb + k) + 1];
        w2[k] = wp2[3 * (cb + k) + 2];
        bc[k] = bp2[cb + k];
        s1c[k] = ss1[cb + k];
        t1c[k] = ss1[256 + cb + k];
    }
    float scP0 = ssP[0], scP1 = ssP[1], scP2 = ssP[2];
    float shP0 = ssP[3], shP1 = ssP[4], shP2 = ssP[5];
    float bw0 = bw1[m], bw16 = bw1[16 + m];
    float jsum0 = 0, jsum1 = 0, jsq0 = 0, jsq1 = 0;
    int swh = cb ^ (rl << 3);        // staging write col (rr&7 == rl, const)
    int swa = (m & 7) << 3;          // MFMA read XOR ((wave*16+m)&7 == m&7)

    // prologue: stage tile 0 into hb0 (combined load+compute+write)
    {
#pragma unroll
        for (int u = 0; u < 8; u++) {
            int rr = rl + u * 8;
            int r = r0 + rr;
            int i = idx[r];
            float4 va = r4[r];
            float rx = fmaxf(scP0 * va.x + shP0, 0.f);
            float ry = fmaxf(scP1 * va.y + shP1, 0.f);
            float rz = fmaxf(scP2 * va.z + shP2, 0.f);
            short8 kv = *(const short8*)(xk + (size_t)i * 256 + cb);
            short8 qv = *(const short8*)(xq + (size_t)(r >> 4) * 256 + cb);
            short8 h;
#pragma unroll
            for (int k = 0; k < 8; k++) {
                float w = s2f(kv[k]) - s2f(qv[k]) + rx * w0[k] + ry * w1[k] + rz * w2[k] + bc[k];
                h[k] = f2bf_bits(fmaxf(s1c[k] * w + t1c[k], 0.f));
            }
            *(short8*)&hb0[rr * 256 + swh] = h;
        }
    }

    for (int it = 0; it < 16; ++it) {
        __syncthreads();   // staging of tile `it` complete (from prev iter / prologue)

        int rbn = r0 + (it + 1) * 64;
        bf16* hbw = (it & 1) ? hb0 : hb1;                 // next buffer
        const bf16* abase = ((it & 1) ? hb1 : hb0) + (wave * 16 + m) * 256;

        // A: issue next tile's random xk gathers (latency hides under B)
        short8 kvs[8];
        if (it < 15) {
#pragma unroll
            for (int u = 0; u < 8; u++) {
                int r = rbn + rl + u * 8;
                kvs[u] = *(const short8*)(xk + (size_t)idx[r] * 256 + cb);
            }
        }

        // B: MFMA from current buffer + nontemporal y2 stores
        floatx4 a0 = (floatx4){bw0, bw0, bw0, bw0};
        floatx4 a1 = (floatx4){bw16, bw16, bw16, bw16};
#pragma unroll
        for (int k = 0; k < 8; k++) {
            int col = (k * 32 + q * 8) ^ swa;
            short8 af = *(const short8*)(abase + col);
            a0 = __builtin_amdgcn_mfma_f32_16x16x32_bf16(af, bf0[k], a0, 0, 0, 0);
            a1 = __builtin_amdgcn_mfma_f32_16x16x32_bf16(af, bf1[k], a1, 0, 0, 0);
        }
        int grow = r0 + it * 64 + wave * 16 + q * 4;
#pragma unroll
        for (int ii = 0; ii < 4; ii++) {
            float y0 = a0[ii];
            float y1 = a1[ii];
            jsum0 += y0; jsq0 += y0 * y0;
            jsum1 += y1; jsq1 += y1 * y1;
            __builtin_nontemporal_store(f2bf_bits(y0),
                (short*)(y2 + (size_t)(grow + ii) * 32 + m));
            __builtin_nontemporal_store(f2bf_bits(y1),
                (short*)(y2 + (size_t)(grow + ii) * 32 + 16 + m));
        }

        // C: finish next tile's rows (cache-friendly loads) and write to LDS
        if (it < 15) {
#pragma unroll
            for (int u = 0; u < 8; u++) {
                int rr = rl + u * 8;
                int r = rbn + rr;
                float4 va = r4[r];
                float rx = fmaxf(scP0 * va.x + shP0, 0.f);
                float ry = fmaxf(scP1 * va.y + shP1, 0.f);
                float rz = fmaxf(scP2 * va.z + shP2, 0.f);
                short8 qv = *(const short8*)(xq + (size_t)(r >> 4) * 256 + cb);
                short8 h;
#pragma unroll
                for (int k = 0; k < 8; k++) {
                    float w = s2f(kvs[u][k]) - s2f(qv[k]) + rx * w0[k] + ry * w1[k] + rz * w2[k] + bc[k];
                    h[k] = f2bf_bits(fmaxf(s1c[k] * w + t1c[k], 0.f));
                }
                *(short8*)&hbw[rr * 256 + swh] = h;
            }
        }
    }

    jsum0 += __shfl_xor(jsum0, 16); jsum0 += __shfl_xor(jsum0, 32);
    jsum1 += __shfl_xor(jsum1, 16); jsum1 += __shfl_xor(jsum1, 32);
    jsq0  += __shfl_xor(jsq0, 16);  jsq0  += __shfl_xor(jsq0, 32);
    jsq1  += __shfl_xor(jsq1, 16);  jsq1  += __shfl_xor(jsq1, 32);
    if (q == 0) {
        atomicAdd(&stats2[m], jsum0);
        atomicAdd(&stats2[16 + m], jsum1);
        atomicAdd(&stats2[32 + m], jsq0);
        atomicAdd(&stats2[48 + m], jsq1);
    }
}

// ---------------------------------------------------------------------------
// final: wave-per-point, zero barriers; BN_p inline; y2 interleaved [CNT][32];
// full occupancy (round-12 cap hurt); nontemporal out stores (write-once
// 64MB stream - keep it from evicting xv gather lines).
// ---------------------------------------------------------------------------
__global__ __launch_bounds__(256) void final_kernel(
    const int* __restrict__ idx, const float4* __restrict__ r4,
    const bf16* __restrict__ xv,
    const float* __restrict__ wp2, const float* __restrict__ bp2,
    const bf16* __restrict__ y2, const float* __restrict__ ss2,
    const bf16* __restrict__ ww2b, const float* __restrict__ bw2,
    const float* __restrict__ ssP, float* __restrict__ out)
{
    __shared__ __align__(16) float wsm[4][16][36];  // [wave][s][j] stride 36 (144B, 16-aligned)
    __shared__ float Asm[4][4][32];                 // [wave][d][j]

    int t = threadIdx.x, wave = t >> 6, lane = t & 63;
    int m = lane & 15, q = lane >> 4;

    // logits B-fragments: ww2b rows m / 16+m (output cols), K-span q*8
    short8 bf0 = *(const short8*)(ww2b + m * 32 + q * 8);
    short8 bf1 = *(const short8*)(ww2b + (16 + m) * 32 + q * 8);
    float bwj0 = bw2[m], bwj1 = bw2[16 + m];

    float s2c[8], t2c[8];
#pragma unroll
    for (int k = 0; k < 8; k++) {
        s2c[k] = ss2[q * 8 + k];
        t2c[k] = ss2[32 + q * 8 + k];
    }
    float scP0 = ssP[0], scP1 = ssP[1], scP2 = ssP[2];
    float shP0 = ssP[3], shP1 = ssP[4], shP2 = ssP[5];

    int c0 = lane * 4;          // this lane's 4 output channels
    int j4 = (lane & 7) * 4;    // j = c & 31
    float wpc0[4], wpc1[4], wpc2[4], bpc[4];
#pragma unroll
    for (int k = 0; k < 4; k++) {
        wpc0[k] = wp2[(c0 + k) * 3];
        wpc1[k] = wp2[(c0 + k) * 3 + 1];
        wpc2[k] = wp2[(c0 + k) * 3 + 2];
        bpc[k]  = bp2[c0 + k];
    }

    int pbase = (blockIdx.x * 4 + wave) * 8;
    for (int pp = 0; pp < 8; pp++) {
        int n = pbase + pp;
        size_t rbase = (size_t)n * 16;

        int iv = idx[rbase + m];   // lanes 0..15 hold the 16 neighbor ids

        // A-frag: z[s=m][u=q*8+k] = relu(bn2(y2))
        short8 yv = *(const short8*)(y2 + (rbase + m) * 32 + q * 8);
        short8 av;
#pragma unroll
        for (int k = 0; k < 8; k++)
            av[k] = f2bf_bits(fmaxf(s2c[k] * s2f(yv[k]) + t2c[k], 0.f));

        floatx4 l0 = (floatx4){bwj0, bwj0, bwj0, bwj0};
        floatx4 l1 = (floatx4){bwj1, bwj1, bwj1, bwj1};
        l0 = __builtin_amdgcn_mfma_f32_16x16x32_bf16(av, bf0, l0, 0, 0, 0);
        l1 = __builtin_amdgcn_mfma_f32_16x16x32_bf16(av, bf1, l1, 0, 0, 0);
        // lane (m,q), reg i: l0[i] = lb[s=q*4+i][j=m], l1[i] = lb[s][j=16+m]

        // softmax over s per column j: lanes {m, m+16, m+32, m+48} hold a column
        float mx0 = fmaxf(fmaxf(l0[0], l0[1]), fmaxf(l0[2], l0[3]));
        float mx1 = fmaxf(fmaxf(l1[0], l1[1]), fmaxf(l1[2], l1[3]));
        mx0 = fmaxf(mx0, __shfl_xor(mx0, 16));
        mx0 = fmaxf(mx0, __shfl_xor(mx0, 32));
        mx1 = fmaxf(mx1, __shfl_xor(mx1, 16));
        mx1 = fmaxf(mx1, __shfl_xor(mx1, 32));
        float w0[4], w1[4];
        float sum0 = 0.f, sum1 = 0.f;
#pragma unroll
        for (int i = 0; i < 4; i++) {
            w0[i] = __expf(l0[i] - mx0); sum0 += w0[i];
            w1[i] = __expf(l1[i] - mx1); sum1 += w1[i];
        }
        sum0 += __shfl_xor(sum0, 16); sum0 += __shfl_xor(sum0, 32);
        sum1 += __shfl_xor(sum1, 16); sum1 += __shfl_xor(sum1, 32);
        float inv0 = 1.f / sum0, inv1 = 1.f / sum1;

        // normalize + A[d][j] partials + stash w to LDS
        float A00 = 0, A10 = 0, A20 = 0, A30 = 0;
        float A01 = 0, A11 = 0, A21 = 0, A31 = 0;
#pragma unroll
        for (int i = 0; i < 4; i++) {
            w0[i] *= inv0; w1[i] *= inv1;
            float4 va = r4[rbase + q * 4 + i];
            float rx = fmaxf(scP0 * va.x + shP0, 0.f);
            float ry = fmaxf(scP1 * va.y + shP1, 0.f);
            float rz = fmaxf(scP2 * va.z + shP2, 0.f);
            A00 += rx * w0[i]; A10 += ry * w0[i];
            A20 += rz * w0[i]; A30 += w0[i];
            A01 += rx * w1[i]; A11 += ry * w1[i];
            A21 += rz * w1[i]; A31 += w1[i];
            wsm[wave][q * 4 + i][m]      = w0[i];
            wsm[wave][q * 4 + i][16 + m] = w1[i];
        }
        A00 += __shfl_xor(A00, 16); A00 += __shfl_xor(A00, 32);
        A10 += __shfl_xor(A10, 16); A10 += __shfl_xor(A10, 32);
        A20 += __shfl_xor(A20, 16); A20 += __shfl_xor(A20, 32);
        A30 += __shfl_xor(A30, 16); A30 += __shfl_xor(A30, 32);
        A01 += __shfl_xor(A01, 16); A01 += __shfl_xor(A01, 32);
        A11 += __shfl_xor(A11, 16); A11 += __shfl_xor(A11, 32);
        A21 += __shfl_xor(A21, 16); A21 += __shfl_xor(A21, 32);
        A31 += __shfl_xor(A31, 16); A31 += __shfl_xor(A31, 32);
        if (q == 0) {
            Asm[wave][0][m] = A00; Asm[wave][1][m] = A10;
            Asm[wave][2][m] = A20; Asm[wave][3][m] = A30;
            Asm[wave][0][16 + m] = A01; Asm[wave][1][16 + m] = A11;
            Asm[wave][2][16 + m] = A21; Asm[wave][3][16 + m] = A31;
        }
        // wave-private LDS: in-order DS pipe + compiler lgkmcnt ordering,
        // no __syncthreads needed.

        // phase D: weighted neighbor sum over the gathered xv rows
        float acc0 = 0, acc1 = 0, acc2 = 0, acc3 = 0;
#pragma unroll
        for (int s = 0; s < 16; s++) {
            int i = __builtin_amdgcn_readlane(iv, s);   // uniform -> SGPR base
            sh4 vv = *(const sh4*)(xv + (size_t)i * 256 + c0);
            float4 wv = *(const float4*)&wsm[wave][s][j4];
            acc0 += s2f(vv[0]) * wv.x;
            acc1 += s2f(vv[1]) * wv.y;
            acc2 += s2f(vv[2]) * wv.z;
            acc3 += s2f(vv[3]) * wv.w;
        }

        float res[4] = {acc0, acc1, acc2, acc3};
#pragma unroll
        for (int k = 0; k < 4; k++) {
            int j = j4 + k;
            res[k] += wpc0[k] * Asm[wave][0][j] + wpc1[k] * Asm[wave][1][j]
                    + wpc2[k] * Asm[wave][2][j] + bpc[k]  * Asm[wave][3][j];
        }
        __builtin_nontemporal_store(
            (floatx4){res[0], res[1], res[2], res[3]},
            (floatx4*)(out + (size_t)n * 256 + c0));
    }
}

// ---------------------------------------------------------------------------
extern "C" void kernel_launch(void* const* d_in, const int* in_sizes, int n_in,
                              void* d_out, int out_size, void* d_ws, size_t ws_size,
                              hipStream_t stream) {
    (void)in_sizes; (void)n_in; (void)out_size; (void)ws_size;

    const float* p   = (const float*)d_in[0];
    const float* x   = (const float*)d_in[1];
    const int*   idx = (const int*)d_in[2];
    const float* wq  = (const float*)d_in[3];  const float* bq  = (const float*)d_in[4];
    const float* wk  = (const float*)d_in[5];  const float* bk  = (const float*)d_in[6];
    const float* wv  = (const float*)d_in[7];  const float* bv  = (const float*)d_in[8];
    const float* wp1 = (const float*)d_in[9];  const float* bp1 = (const float*)d_in[10];
    const float* gp  = (const float*)d_in[11]; const float* btp = (const float*)d_in[12];
    const float* wp2 = (const float*)d_in[13]; const float* bp2 = (const float*)d_in[14];
    const float* g1  = (const float*)d_in[15]; const float* b1  = (const float*)d_in[16];
    const float* ww1 = (const float*)d_in[17]; const float* bw1 = (const float*)d_in[18];
    const float* g2  = (const float*)d_in[19]; const float* b2  = (const float*)d_in[20];
    const float* ww2 = (const float*)d_in[21]; const float* bw2 = (const float*)d_in[22];
    float* out = (float*)d_out;

    // workspace layout
    float* fws    = (float*)d_ws;
    float* statsP = fws;            // 96 floats: 6 accumulators at stride 16
    float* ssP    = fws + 96;       // 6
    float* stats1 = fws + 112;      // 512
    float* ss1    = fws + 624;      // 512
    float* stats2 = fws + 1136;     // 64
    float* ss2    = fws + 1200;     // 64  (ends at float 1264 = byte 5056)
    bf16* ww2b = (bf16*)((char*)d_ws + 6144);          // 1024 bf16 = 2048 B (ends at 8192)
    bf16* Wcat = (bf16*)((char*)d_ws + 8192);          // 768*256 bf16 = 393216 B
    bf16* xq = (bf16*)((char*)d_ws + 401408);
    bf16* xk = xq + (size_t)NPTS * CH;
    bf16* xv = xk + (size_t)NPTS * CH;
    bf16* y2 = xv + (size_t)NPTS * CH;                 // CNT*32 bf16 (64 MB)
    float4* r4 = (float4*)(y2 + (size_t)CNT * 32);     // CNT float4
    // xb (bf16 x, 32 MB) aliases the y2 region: needed only between fused0
    // and gemm; y2 is first written much later (stats2).
    bf16* xb = y2;
    // total ~185 MB

    hipMemsetAsync(d_ws, 0, 8192, stream);

    fused0_kernel<<<1024 + 97 + 8192, 256, 0, stream>>>(
        wq, wk, wv, ww2, x, p, idx, wp1, bp1, Wcat, ww2b, xb, statsP, r4);
    gemm_kernel<<<dim3(512, 6), 256, 0, stream>>>(xb, Wcat, bq, bk, bv, xq, xk, xv);
    finalize_kernel<<<1, 256, 0, stream>>>(statsP, gp, btp, ssP, 3, 16);
    stats1_kernel<<<1024, 256, 0, stream>>>(idx, r4, xk, xq, wp2, bp2, ssP, stats1);
    finalize_kernel<<<1, 256, 0, stream>>>(stats1, g1, b1, ss1, 256, 1);
    stats2_kernel<<<1024, 256, 0, stream>>>(idx, r4, xk, xq, wp2, bp2, ssP, ss1, ww1, bw1, y2, stats2);
    finalize_kernel<<<1, 256, 0, stream>>>(stats2, g2, b2, ss2, 32, 1);
    final_kernel<<<NPTS / 32, 256, 0, stream>>>(idx, r4, xv, wp2, bp2, y2, ss2, ww2b, bw2, ssP, out);
}